// Round 5
// baseline (222.927 us; speedup 1.0000x reference)
//
#include <hip/hip_runtime.h>

#define S_LEN  2048
#define NHEAD  16
#define HDIM   64
#define DMODEL 1024
#define XN     (4 * 2048 * 1024)   // x elements (8388608)
#define WN     (1024 * 1024)       // per-W elements

typedef float  floatx4 __attribute__((ext_vector_type(4)));
typedef __bf16 bf16x8  __attribute__((ext_vector_type(8)));
typedef __bf16 bf16x4  __attribute__((ext_vector_type(4)));
typedef unsigned int u32;

union B8 {
  bf16x8 v8;
  bf16x4 v4[2];
  __bf16 e[8];
  uint4  u;
};

// async global->LDS 16B copy: LDS dest = wave-uniform base + lane*16
typedef __attribute__((address_space(1))) u32 gu32;
typedef __attribute__((address_space(3))) u32 lu32;
__device__ __forceinline__ void gld16(const void* g, void* l) {
  __builtin_amdgcn_global_load_lds((const gu32*)g, (lu32*)l, 16, 0, 0);
}

// ---------------------------------------------------------------------------
// Prepass: fp32 -> bf16 (Wq pre-scaled by log2(e)/sqrt(1024)).
// ---------------------------------------------------------------------------
__global__ __launch_bounds__(256) void cvt_kernel(
    const float* __restrict__ x,  const float* __restrict__ Wq,
    const float* __restrict__ Wk, const float* __restrict__ Wv,
    __bf16* __restrict__ xb, __bf16* __restrict__ Wb)
{
  const size_t base = ((size_t)blockIdx.x * 256 + threadIdx.x) * 8;
  const float* src;
  __bf16* dst;
  float scl = 1.0f;
  if (base < XN) {
    src = x + base;
    dst = xb + base;
  } else {
    const size_t j = base - XN;
    const int mat = (int)(j >> 20);
    const size_t o = j & (WN - 1);
    src = (mat == 0 ? Wq : mat == 1 ? Wk : Wv) + o;
    dst = Wb + ((size_t)mat << 20) + o;
    if (mat == 0) scl = 0.045084220027780106f;  // log2(e)/32
  }
  float4 a = *(const float4*)src;
  float4 b = *(const float4*)(src + 4);
  B8 r;
  r.e[0] = (__bf16)(a.x * scl); r.e[1] = (__bf16)(a.y * scl);
  r.e[2] = (__bf16)(a.z * scl); r.e[3] = (__bf16)(a.w * scl);
  r.e[4] = (__bf16)(b.x * scl); r.e[5] = (__bf16)(b.y * scl);
  r.e[6] = (__bf16)(b.z * scl); r.e[7] = (__bf16)(b.w * scl);
  *(bf16x8*)dst = r.v8;
}

// ---------------------------------------------------------------------------
// Projection GEMM: Y = Xb * Wb^T, 128x128 tile, BK=32, 16x16x32 bf16 MFMA.
// Double-buffered global_load_lds staging (prefetch K-step k+1 during k).
// LDS: unpadded + XOR granule swizzle. Epilogue bounces through LDS.
// V written transposed [bh][hd][s'] with per-64-block permutation
// s' = sigma^-1(s) (bakes PV register reinterpretation order into V rows).
// ---------------------------------------------------------------------------
__global__ __launch_bounds__(256) void proj_kernel(
    const __bf16* __restrict__ xb, const __bf16* __restrict__ Wb,
    __bf16* __restrict__ Qo, __bf16* __restrict__ Ko, __bf16* __restrict__ Vt)
{
  __shared__ __attribute__((aligned(16))) union {
    struct { __bf16 As[2][128 * 32]; __bf16 Bs[2][128 * 32]; } st;  // 32 KB
    __bf16 Es[4][64][72];   // epilogue bounce (36.8 KB) — sets LDS size
  } sh;

  const int tid  = threadIdx.x;
  const int lane = tid & 63;
  const int wv   = tid >> 6;
  const int l15  = lane & 15;
  const int quad = lane >> 4;

  const int row0 = blockIdx.y * 128;   // m tile
  const int n0   = blockIdx.x * 128;   // n tile (0..3071)
  const int wrow = (wv >> 1) * 64;
  const int wcol = (wv & 1) * 64;

  floatx4 acc[4][4];
  #pragma unroll
  for (int i = 0; i < 4; i++)
    #pragma unroll
    for (int j = 0; j < 4; j++) acc[i][j] = (floatx4)0.0f;

  const int swz = quad ^ ((l15 >> 1) & 3);   // fragment-read physical granule

  // staging lambda-equivalent (macro-free, inlined twice)
  const int c0    = tid;              // granule ids tid, tid+256
  const int r0_   = c0 >> 2;
  const int g0    = (c0 & 3) ^ ((c0 >> 3) & 3);
  const int c1    = tid + 256;
  const int r1_   = c1 >> 2;
  const int g1    = (c1 & 3) ^ ((c1 >> 3) & 3);
  const size_t l0 = (size_t)(wv * 64) * 8;          // wave-uniform LDS offs
  const size_t l1 = (size_t)(wv * 64 + 256) * 8;

  // preload kk=0 into buffer 0
  {
    gld16(xb + (size_t)(row0 + r0_) * DMODEL + 0 + g0 * 8, sh.st.As[0] + l0);
    gld16(Wb + (size_t)(n0 + r0_) * DMODEL + 0 + g0 * 8, sh.st.Bs[0] + l0);
    gld16(xb + (size_t)(row0 + r1_) * DMODEL + 0 + g1 * 8, sh.st.As[0] + l1);
    gld16(Wb + (size_t)(n0 + r1_) * DMODEL + 0 + g1 * 8, sh.st.Bs[0] + l1);
  }

  int buf = 0;
  for (int kk = 0; kk < DMODEL; kk += 32) {
    __syncthreads();   // drains this buffer's loads (hidden by prev compute)
    if (kk + 32 < DMODEL) {
      const int nb_ = buf ^ 1;
      const int k2  = kk + 32;
      gld16(xb + (size_t)(row0 + r0_) * DMODEL + k2 + g0 * 8, sh.st.As[nb_] + l0);
      gld16(Wb + (size_t)(n0 + r0_) * DMODEL + k2 + g0 * 8, sh.st.Bs[nb_] + l0);
      gld16(xb + (size_t)(row0 + r1_) * DMODEL + k2 + g1 * 8, sh.st.As[nb_] + l1);
      gld16(Wb + (size_t)(n0 + r1_) * DMODEL + k2 + g1 * 8, sh.st.Bs[nb_] + l1);
    }

    B8 af[4], bg[4];
    #pragma unroll
    for (int mb = 0; mb < 4; mb++)
      af[mb].u = *(const uint4*)(sh.st.As[buf] + (size_t)(wrow + mb * 16 + l15) * 32 + swz * 8);
    #pragma unroll
    for (int nb = 0; nb < 4; nb++)
      bg[nb].u = *(const uint4*)(sh.st.Bs[buf] + (size_t)(wcol + nb * 16 + l15) * 32 + swz * 8);

    #pragma unroll
    for (int mb = 0; mb < 4; mb++)
      #pragma unroll
      for (int nb = 0; nb < 4; nb++)
        acc[mb][nb] = __builtin_amdgcn_mfma_f32_16x16x32_bf16(
            af[mb].v8, bg[nb].v8, acc[mb][nb], 0, 0, 0);
    buf ^= 1;
  }

  // ---------------- epilogue (LDS bounce, per-wave private Es[wv]) ----------
  const int mat   = n0 >> 10;                    // 0=Q 1=K 2=V (block-uniform)
  const int bb    = (row0 + wrow) >> 11;         // batch
  const int sbase = (row0 + wrow) & 2047;        // 64-aligned s window
  const int hh    = ((n0 & 1023) + wcol) >> 6;   // head (window is 64-aligned)
  __syncthreads();                               // safe to reuse union

  if (mat < 2) {
    // layout [s][d]: scalar writes, then fully-coalesced row-major readout
    #pragma unroll
    for (int mb = 0; mb < 4; mb++)
      #pragma unroll
      for (int rr = 0; rr < 4; rr++)
        #pragma unroll
        for (int nb = 0; nb < 4; nb++)
          sh.Es[wv][mb * 16 + quad * 4 + rr][nb * 16 + l15] =
              (__bf16)acc[mb][nb][rr];
    // Es[wv] is wave-private: no barrier needed
    __bf16* Out = (mat == 0) ? Qo : Ko;
    const size_t obase = ((size_t)(bb * NHEAD + hh) * S_LEN + sbase) * HDIM;
    #pragma unroll
    for (int t = 0; t < 8; t++) {
      const int lin = t * 64 + lane;
      const int s = lin >> 3, g = lin & 7;
      *(uint4*)&Out[obase + (size_t)s * HDIM + g * 8] =
          *(const uint4*)&sh.Es[wv][s][g * 8];
    }
  } else {
    // layout [d][s']: s6 = mb*16+quad*4+rr -> column sigma^-1(s6)
    //   = 32*(mb>>1) + 16*(quad>>1) + 8*(quad&1) + 4*(mb&1) + rr   (b64 write)
    #pragma unroll
    for (int mb = 0; mb < 4; mb++)
      #pragma unroll
      for (int nb = 0; nb < 4; nb++) {
        bf16x4 pk = { (__bf16)acc[mb][nb][0], (__bf16)acc[mb][nb][1],
                      (__bf16)acc[mb][nb][2], (__bf16)acc[mb][nb][3] };
        const int col = 32 * (mb >> 1) + 16 * (quad >> 1) + 8 * (quad & 1) +
                        4 * (mb & 1);
        *(bf16x4*)&sh.Es[wv][nb * 16 + l15][col] = pk;
      }
    const size_t vbase = (size_t)(bb * NHEAD + hh) * HDIM * S_LEN;
    #pragma unroll
    for (int t = 0; t < 8; t++) {
      const int lin = t * 64 + lane;
      const int d = lin >> 3, g = lin & 7;
      *(uint4*)&Vt[vbase + (size_t)d * S_LEN + sbase + g * 8] =
          *(const uint4*)&sh.Es[wv][d][g * 8];
    }
  }
}

// ---------------------------------------------------------------------------
// Flash attention, fixed-max softmax, register-resident P, double-buffered
// KV staging:
//   barrier; prefetch tile t+1 -> buf^1; compute tile t from buf.
// The vmcnt(0)+barrier drain for tile t+1 then lands AFTER ~1300 cyc of
// compute -> load latency fully hidden (this was the exposed stall).
//   S^T = K Q^T (A=K, B=Q); P^T built in-register; O^T = V^T P^T.
// Block = 256 q rows (4 waves x 64); KV tile 64; LDS = 2*(Ks+Vs) = 32 KB.
// Grid (bh, qi): all q-tiles of one bh land on one XCD (K/V L2 locality).
// ---------------------------------------------------------------------------
__global__ __launch_bounds__(256, 2) void attn_kernel(
    const __bf16* __restrict__ Q, const __bf16* __restrict__ K,
    const __bf16* __restrict__ Vt, float* __restrict__ out)
{
  __shared__ __attribute__((aligned(16))) __bf16 Ks[2][64 * 64];
  __shared__ __attribute__((aligned(16))) __bf16 Vs[2][64 * 64];

  const int tid  = threadIdx.x;
  const int lane = tid & 63;
  const int wv   = tid >> 6;
  const int l15  = lane & 15;
  const int quad = lane >> 4;

  const int bh = blockIdx.x;           // fast dim -> XCD = bh % 8
  const int q0 = blockIdx.y * 256;
  const int b  = bh >> 4;
  const int h  = bh & 15;

  const __bf16* Qb = Q  + (size_t)bh * S_LEN * HDIM;
  const __bf16* Kb = K  + (size_t)bh * S_LEN * HDIM;
  const __bf16* Vb = Vt + (size_t)bh * HDIM * S_LEN;   // [hd][s']

  // Q fragments (B-operand: n=q, k=d), resident all loop
  B8 aq[4][2];
  #pragma unroll
  for (int nb = 0; nb < 4; nb++)
    #pragma unroll
    for (int kc = 0; kc < 2; kc++)
      aq[nb][kc].u = *(const uint4*)
          &Qb[(size_t)(q0 + wv * 64 + nb * 16 + l15) * HDIM + kc * 32 + quad * 8];

  floatx4 o[4][4];   // [mt=d-tile][nb=q-tile], C-layout col=q row=d
  float rs[4];       // per-lane partial row sums, q = nb*16+l15
  #pragma unroll
  for (int mt = 0; mt < 4; mt++)
    #pragma unroll
    for (int nb = 0; nb < 4; nb++) o[mt][nb] = (floatx4)0.0f;
  #pragma unroll
  for (int nb = 0; nb < 4; nb++) rs[nb] = 0.0f;

  const int swz0 = quad ^ (l15 & 7);       // kc=0 physical granule
  const int swz1 = (4 + quad) ^ (l15 & 7); // kc=1

  // staging address components (granules tid, tid+256)
  const int rA  = tid >> 3;
  const int gA  = (tid & 7) ^ ((tid >> 3) & 7);
  const int rB  = (tid + 256) >> 3;
  const int gB  = ((tid + 256) & 7) ^ (((tid + 256) >> 3) & 7);
  const size_t lA = (size_t)(wv * 64) * 8;          // wave-uniform LDS offs
  const size_t lB = (size_t)(wv * 64 + 256) * 8;

  // preload tile 0 into buffer 0
  {
    gld16(Kb + (size_t)rA * HDIM + gA * 8, Ks[0] + lA);
    gld16(Vb + (size_t)rA * S_LEN + gA * 8, Vs[0] + lA);
    gld16(Kb + (size_t)rB * HDIM + gB * 8, Ks[0] + lB);
    gld16(Vb + (size_t)rB * S_LEN + gB * 8, Vs[0] + lB);
  }

  int buf = 0;
  for (int kv0 = 0; kv0 < S_LEN; kv0 += 64) {
    __syncthreads();   // drains buf's loads (latency hidden by prev compute)
    if (kv0 + 64 < S_LEN) {
      const int nbuf = buf ^ 1;
      const int kv1  = kv0 + 64;
      gld16(Kb + (size_t)(kv1 + rA) * HDIM + gA * 8, Ks[nbuf] + lA);
      gld16(Vb + (size_t)rA * S_LEN + kv1 + gA * 8, Vs[nbuf] + lA);
      gld16(Kb + (size_t)(kv1 + rB) * HDIM + gB * 8, Ks[nbuf] + lB);
      gld16(Vb + (size_t)rB * S_LEN + kv1 + gB * 8, Vs[nbuf] + lB);
    }

    // S^T = K Q^T: sa[t][nb], t = kv 16-block, nb = q 16-block
    floatx4 sa[4][4];
    #pragma unroll
    for (int t = 0; t < 4; t++)
      #pragma unroll
      for (int nb = 0; nb < 4; nb++) sa[t][nb] = (floatx4)0.0f;

    #pragma unroll
    for (int kc = 0; kc < 2; kc++) {
      const int sw = kc ? swz1 : swz0;
      B8 ak[4];
      #pragma unroll
      for (int t = 0; t < 4; t++)
        ak[t].u = *(const uint4*)(Ks[buf] + (size_t)(t * 16 + l15) * 64 + sw * 8);
      #pragma unroll
      for (int t = 0; t < 4; t++)
        #pragma unroll
        for (int nb = 0; nb < 4; nb++)
          sa[t][nb] = __builtin_amdgcn_mfma_f32_16x16x32_bf16(
              ak[t].v8, aq[nb][kc].v8, sa[t][nb], 0, 0, 0);
    }

    // P^T fragments in-register + PV, per k-chunk
    #pragma unroll
    for (int kc = 0; kc < 2; kc++) {
      const int sw = kc ? swz1 : swz0;
      B8 pf[4];
      #pragma unroll
      for (int nb = 0; nb < 4; nb++) {
        float e0 = __builtin_amdgcn_exp2f(sa[2 * kc][nb][0]);
        float e1 = __builtin_amdgcn_exp2f(sa[2 * kc][nb][1]);
        float e2 = __builtin_amdgcn_exp2f(sa[2 * kc][nb][2]);
        float e3 = __builtin_amdgcn_exp2f(sa[2 * kc][nb][3]);
        float e4 = __builtin_amdgcn_exp2f(sa[2 * kc + 1][nb][0]);
        float e5 = __builtin_amdgcn_exp2f(sa[2 * kc + 1][nb][1]);
        float e6 = __builtin_amdgcn_exp2f(sa[2 * kc + 1][nb][2]);
        float e7 = __builtin_amdgcn_exp2f(sa[2 * kc + 1][nb][3]);
        rs[nb] += ((e0 + e1) + (e2 + e3)) + ((e4 + e5) + (e6 + e7));
        pf[nb].e[0] = (__bf16)e0; pf[nb].e[1] = (__bf16)e1;
        pf[nb].e[2] = (__bf16)e2; pf[nb].e[3] = (__bf16)e3;
        pf[nb].e[4] = (__bf16)e4; pf[nb].e[5] = (__bf16)e5;
        pf[nb].e[6] = (__bf16)e6; pf[nb].e[7] = (__bf16)e7;
      }
      B8 av[4];
      #pragma unroll
      for (int mt = 0; mt < 4; mt++)
        av[mt].u = *(const uint4*)(Vs[buf] + (size_t)(mt * 16 + l15) * 64 + sw * 8);
      #pragma unroll
      for (int mt = 0; mt < 4; mt++)
        #pragma unroll
        for (int nb = 0; nb < 4; nb++)
          o[mt][nb] = __builtin_amdgcn_mfma_f32_16x16x32_bf16(
              av[mt].v8, pf[nb].v8, o[mt][nb], 0, 0, 0);
    }
    buf ^= 1;
  }

  // epilogue: O^T C-layout col=q(l15,nb) row=d(quad*4+r, mt); rs over quads
  #pragma unroll
  for (int nb = 0; nb < 4; nb++) {
    float v = rs[nb];
    v += __shfl_xor(v, 16);
    v += __shfl_xor(v, 32);
    const float inv = 1.0f / v;
    const int q = q0 + wv * 64 + nb * 16 + l15;
    #pragma unroll
    for (int mt = 0; mt < 4; mt++) {
      float4 w = { o[mt][nb][0] * inv, o[mt][nb][1] * inv,
                   o[mt][nb][2] * inv, o[mt][nb][3] * inv };
      *(float4*)&out[((size_t)(b * S_LEN + q)) * DMODEL + h * HDIM +
                     mt * 16 + quad * 4] = w;
    }
  }
}

extern "C" void kernel_launch(void* const* d_in, const int* in_sizes, int n_in,
                              void* d_out, int out_size, void* d_ws, size_t ws_size,
                              hipStream_t stream) {
  const float* x  = (const float*)d_in[0];
  const float* Wq = (const float*)d_in[1];
  const float* Wk = (const float*)d_in[2];
  const float* Wv = (const float*)d_in[3];
  float* out = (float*)d_out;

  __bf16* xb = (__bf16*)d_ws;            // 8.4M elems
  __bf16* Wb = xb + XN;                  // 3.1M elems ([3072][1024])
  __bf16* Q  = Wb + 3 * (size_t)WN;      // 8.4M
  __bf16* K  = Q + (size_t)XN;
  __bf16* Vt = K + (size_t)XN;           // total ~73 MB

  dim3 b256(256);
  cvt_kernel<<<dim3((XN + 3 * WN) / (256 * 8)), b256, 0, stream>>>(
      x, Wq, Wk, Wv, xb, Wb);

  dim3 g1(24, 64);
  proj_kernel<<<g1, b256, 0, stream>>>(xb, Wb, Q, K, Vt);

  dim3 g2(64, 8);   // x = bh (XCD-local K/V), y = q-tile
  attn_kernel<<<g2, b256, 0, stream>>>(Q, K, Vt, out);
}